// Round 9
// baseline (164.086 us; speedup 1.0000x reference)
//
#include <hip/hip_runtime.h>

typedef unsigned short u16;
typedef __bf16 bf16x8 __attribute__((ext_vector_type(8)));
typedef float f32x4 __attribute__((ext_vector_type(4)));
typedef unsigned short us4 __attribute__((ext_vector_type(4)));

#define MFMA16(a, b, c) __builtin_amdgcn_mfma_f32_16x16x32_bf16((a), (b), (c), 0, 0, 0)

__device__ __forceinline__ unsigned short f2bf(float f) {
  unsigned u = __builtin_bit_cast(unsigned, f);
  u += 0x7fffu + ((u >> 16) & 1u);
  return (unsigned short)(u >> 16);
}
__device__ __forceinline__ float bf2f(unsigned short s) {
  unsigned u = ((unsigned)s) << 16;
  return __builtin_bit_cast(float, u);
}
__device__ __forceinline__ unsigned cvtpk_bf16(float a, float b) {
  unsigned r;
  asm("v_cvt_pk_bf16_f32 %0, %1, %2" : "=v"(r) : "v"(a), "v"(b));
  return r;
}
__device__ __forceinline__ float exp2_fast(float x) {
  float r;
  asm("v_exp_f32 %0, %1" : "=v"(r) : "v"(x));
  return r;
}
__device__ __forceinline__ bf16x8 combine2us4(us4 lo, us4 hi) {
  union { us4 h[2]; bf16x8 v; } u;
  u.h[0] = lo; u.h[1] = hi;
  return u.v;
}
__device__ __forceinline__ bf16x8 combine4w(unsigned a, unsigned b, unsigned c, unsigned d) {
  union { unsigned w[4]; bf16x8 v; } u;
  u.w[0] = a; u.w[1] = b; u.w[2] = c; u.w[3] = d;
  return u.v;
}
__device__ __forceinline__ void gload_lds16(const void* g, void* l) {
  __builtin_amdgcn_global_load_lds(
      (__attribute__((address_space(1))) void*)(unsigned long long)g,
      (__attribute__((address_space(3))) void*)l, 16, 0, 0);
}

// softmax scale folded with log2(e):  (1/sqrt(64)) * log2(e)
#define QSCALE 0.1803368801111601f
// -1e9 * log2(e)  (mask bias directly in exp2 domain)
#define MBIAS_L2E -1.442695040e9f

// ---------------- fused prep: mask prep + all f32->bf16 conversions ----------
// Replaces 4 launches (prep_mask + 3x cvt) with one. Blocks 0..31 additionally
// handle the 8192-entry mask (dtype detection as before). Grid-stride cvt over
// the concatenated x (2097152 f32x4), w_in (786432), w_out (262144) segments.
__global__ void fused_prep_kernel(
    const float* __restrict__ x, const float* __restrict__ w_in,
    const float* __restrict__ w_out, const void* __restrict__ mask,
    u16* __restrict__ xb, u16* __restrict__ w_in_b, u16* __restrict__ w_out_b,
    float* __restrict__ mbias, float* __restrict__ mmul) {
  int tid = blockIdx.x * 256 + threadIdx.x;
  if (blockIdx.x < 32) {
    int i = tid;  // 0..8191
    const int* m32 = (const int*)mask;
    const float* mf = (const float*)mask;
    const unsigned char* m8 = (const unsigned char*)mask;
    bool i32ok = true, f32ok = true;
    for (int s = 0; s < 64; ++s) {
      int idx = s * 29 + 1;
      int v = m32[idx];
      float f = mf[idx];
      i32ok = i32ok && (v == 0 || v == 1);
      f32ok = f32ok && (f == 0.0f || f == 1.0f);
    }
    int val;
    if (i32ok) val = m32[i];
    else if (f32ok) val = (mf[i] != 0.0f) ? 1 : 0;
    else val = m8[i] ? 1 : 0;
    mbias[i] = val ? 0.0f : MBIAS_L2E;
    mmul[i] = val ? 1.0f : 0.0f;
  }
  const int stride = 2048 * 256;
  for (int i = tid; i < 3145728; i += stride) {
    const float* src;
    u16* dst;
    int off;
    if (i < 2097152) { src = x; dst = xb; off = i; }
    else if (i < 2883584) { src = w_in; dst = w_in_b; off = i - 2097152; }
    else { src = w_out; dst = w_out_b; off = i - 2883584; }
    f32x4 v = ((const f32x4*)src)[off];
    us4 o;
    o[0] = f2bf(v[0]); o[1] = f2bf(v[1]); o[2] = f2bf(v[2]); o[3] = f2bf(v[3]);
    ((us4*)dst)[off] = o;
  }
}

// ---------------- 128x128x(K=1024) bf16 MFMA GEMM mainloop -------------------
// Double-buffered (2 x 32KB LDS) with counted waits, wait-own-then-barrier:
// per iter {stage(t+1) -> buf^1; vmcnt(8); barrier; comp(t); barrier}.
// Never vmcnt(0) in-loop (r6: removed the ~20% __syncthreads drain stall).
__device__ __forceinline__ void gemm128_mainloop(
    const u16* __restrict__ Ag, const u16* __restrict__ Bg,
    int m0, int n0, char* Ls, f32x4 (&acc)[4][4]) {
  const int t = threadIdx.x;
  const int wave = t >> 6, lane = t & 63;
  const int g = lane >> 4, q16 = lane & 15;
  const int wr = wave >> 1, wc = wave & 1;

#pragma unroll
  for (int i = 0; i < 4; ++i)
#pragma unroll
    for (int j = 0; j < 4; ++j) acc[i][j] = (f32x4){0.f, 0.f, 0.f, 0.f};

  auto stage = [&](int kt, int bsel) {  // 8 gload_lds per thread
#pragma unroll
    for (int i = 0; i < 4; ++i) {
      int c = i * 256 + t;
      int row = c >> 3;
      int gch = (c & 7) ^ (row & 7);
      gload_lds16(Ag + (size_t)(m0 + row) * 1024 + kt * 64 + gch * 8,
                  Ls + bsel + i * 4096 + wave * 1024);
    }
#pragma unroll
    for (int i = 0; i < 4; ++i) {
      int c = i * 256 + t;
      int row = c >> 3;
      int gch = (c & 7) ^ (row & 7);
      gload_lds16(Bg + (size_t)(n0 + row) * 1024 + kt * 64 + gch * 8,
                  Ls + bsel + 16384 + i * 4096 + wave * 1024);
    }
  };

  auto comp = [&](int bsel) {
    const char* As = Ls + bsel;
    const char* Bs = Ls + bsel + 16384;
#pragma unroll
    for (int ks = 0; ks < 2; ++ks) {
      bf16x8 af[4], bfr[4];
#pragma unroll
      for (int mi = 0; mi < 4; ++mi) {
        int row = wr * 64 + mi * 16 + q16;
        int ch = (ks * 4 + g) ^ (row & 7);
        af[mi] = *(const bf16x8*)(As + row * 128 + ch * 16);
      }
#pragma unroll
      for (int ni = 0; ni < 4; ++ni) {
        int row = wc * 64 + ni * 16 + q16;
        int ch = (ks * 4 + g) ^ (row & 7);
        bfr[ni] = *(const bf16x8*)(Bs + row * 128 + ch * 16);
      }
      __builtin_amdgcn_s_setprio(1);
#pragma unroll
      for (int mi = 0; mi < 4; ++mi)
#pragma unroll
        for (int ni = 0; ni < 4; ++ni)
          acc[mi][ni] = MFMA16(af[mi], bfr[ni], acc[mi][ni]);
      __builtin_amdgcn_s_setprio(0);
    }
  };

  stage(0, 0);
#pragma unroll 1
  for (int kt = 0; kt < 15; ++kt) {
    const int bsel = (kt & 1) << 15;
    stage(kt + 1, bsel ^ 32768);
    asm volatile("s_waitcnt vmcnt(8)" ::: "memory");
    __builtin_amdgcn_sched_barrier(0);
    __builtin_amdgcn_s_barrier();
    __builtin_amdgcn_sched_barrier(0);
    comp(bsel);
    __builtin_amdgcn_s_barrier();
    __builtin_amdgcn_sched_barrier(0);
  }
  asm volatile("s_waitcnt vmcnt(0)" ::: "memory");
  __builtin_amdgcn_sched_barrier(0);
  __builtin_amdgcn_s_barrier();
  __builtin_amdgcn_sched_barrier(0);
  comp(32768);  // kt = 15 -> buf 1
}

// XCD-chunked bijective block swizzle (nwg % 8 == 0): keeps same-A-panel
// blocks (same by) on one XCD's L2.
__device__ __forceinline__ void xcd_swizzle(int gx, int gy, int& bx, int& by) {
  int lin = blockIdx.x + gx * blockIdx.y;
  int cpx = (gx * gy) >> 3;
  int sw = (lin & 7) * cpx + (lin >> 3);
  bx = sw % gx;
  by = sw / gx;
}

// ---------------- GEMM1: qkv = x @ w_in^T + b_in (+ fused RoPE) --------------
// q pre-scaled by QSCALE; v written TRANSPOSED into vt[bh][d][n'] (packed us4,
// within-32-key permutation n' = (n&~31)|((n>>2)&3)<<3|((n>>4)&1)<<2).
// NEW (r9): RoPE fused into the epilogue for head-0 waves (wave-uniform
// wc==0 && (n0&1023)==0, blocks bx in {0,8} only). The rotation pair
// (dd, dd+1) sits in adjacent lanes (lane^1 flips q16 bit0 only: same
// g/mi/r/ni), so v' = v*cos(f) -/+ shfl_xor(v,1)*sin(f), f=freqs[nn*64+dd].
// Even lane = x0 path (-sin), odd = x1 path (+sin); commutes with QSCALE.
// Replaces the rope_kernel launch + its 4MB global RMW pass.
__global__ __launch_bounds__(256) void gemm_qkv_kernel(
    const u16* __restrict__ A, const u16* __restrict__ B, const float* __restrict__ bias,
    const float* __restrict__ freqs,
    u16* __restrict__ qb, u16* __restrict__ kb, u16* __restrict__ vt) {
  __shared__ __align__(16) char Ls[65536];
  int bx, by;
  xcd_swizzle(24, 64, bx, by);
  const int m0 = by * 128, n0 = bx * 128;
  f32x4 acc[4][4];
  gemm128_mainloop(A, B, m0, n0, Ls, acc);
  const int t = threadIdx.x, wave = t >> 6, lane = t & 63, g = lane >> 4, q16 = lane & 15;
  const int wr = wave >> 1, wc = wave & 1;
  const int seg = n0 >> 10;  // 0=q, 1=k, 2=v (uniform per block)
  if (seg < 2) {
    u16* dst = seg ? kb : qb;
    float sc = seg ? 1.0f : QSCALE;
    const bool ropeW = (wc == 0) && ((n0 & 1023) == 0);  // head-0 wave (uniform)
    if (ropeW) {
#pragma unroll
      for (int ni = 0; ni < 4; ++ni) {
        int c = n0 + ni * 16 + q16;        // wc == 0
        float bv = bias[c];
        int dd = c & 63;                   // head-0: dd == cc, hh == 0
#pragma unroll
        for (int mi = 0; mi < 4; ++mi) {
#pragma unroll
          for (int r = 0; r < 4; ++r) {
            int m = m0 + wr * 64 + mi * 16 + 4 * g + r;
            int bb = m >> 11, nn = m & 2047;
            float v = (acc[mi][ni][r] + bv) * sc;
            float vp = __shfl_xor(v, 1);
            float f = freqs[nn * 64 + dd];
            float sn, cs;
            __sincosf(f, &sn, &cs);
            float rot = (q16 & 1) ? (v * cs + vp * sn) : (v * cs - vp * sn);
            dst[((size_t)(bb * 16) * 2048 + nn) * 64 + dd] = f2bf(rot);
          }
        }
      }
    } else {
#pragma unroll
      for (int ni = 0; ni < 4; ++ni) {
        int c = n0 + wc * 64 + ni * 16 + q16;
        float bv = bias[c];
        int cc = c & 1023, hh = cc >> 6, dd = cc & 63;
#pragma unroll
        for (int mi = 0; mi < 4; ++mi) {
#pragma unroll
          for (int r = 0; r < 4; ++r) {
            int m = m0 + wr * 64 + mi * 16 + 4 * g + r;
            int bb = m >> 11, nn = m & 2047;
            dst[((size_t)(bb * 16 + hh) * 2048 + nn) * 64 + dd] =
                f2bf((acc[mi][ni][r] + bv) * sc);
          }
        }
      }
    }
  } else {
#pragma unroll
    for (int ni = 0; ni < 4; ++ni) {
      int c = n0 + wc * 64 + ni * 16 + q16;
      float bv = bias[c];
      int cc = c & 1023, hh = cc >> 6, dd = cc & 63;
#pragma unroll
      for (int mi = 0; mi < 4; ++mi) {
        int mbase = m0 + wr * 64 + mi * 16 + 4 * g;
        int bb = mbase >> 11, nn = mbase & 2047;
        // within-32 key permutation (bijective on us4 groups)
        int nnp = (nn & ~31) | (((nn >> 2) & 3) << 3) | (((nn >> 4) & 1) << 2);
        us4 pk;
#pragma unroll
        for (int r = 0; r < 4; ++r) pk[r] = f2bf(acc[mi][ni][r] + bv);
        *(us4*)(vt + ((size_t)((bb * 16 + hh) * 64 + dd)) * 2048 + nnp) = pk;
      }
    }
  }
}

// ---------------- GEMM3: out = attn_out @ w_out^T + b_out, * maskMul ----------------
__global__ __launch_bounds__(256) void gemm_out_kernel(
    const u16* __restrict__ A, const u16* __restrict__ B, const float* __restrict__ bias,
    const float* __restrict__ maskMul, float* __restrict__ out) {
  __shared__ __align__(16) char Ls[65536];
  int bx, by;
  xcd_swizzle(8, 64, bx, by);
  const int m0 = by * 128, n0 = bx * 128;
  f32x4 acc[4][4];
  gemm128_mainloop(A, B, m0, n0, Ls, acc);
  const int t = threadIdx.x, wave = t >> 6, lane = t & 63, g = lane >> 4, q16 = lane & 15;
  const int wr = wave >> 1, wc = wave & 1;
#pragma unroll
  for (int mi = 0; mi < 4; ++mi) {
#pragma unroll
    for (int r = 0; r < 4; ++r) {
      int m = m0 + wr * 64 + mi * 16 + 4 * g + r;
      float mm = maskMul[m];
#pragma unroll
      for (int ni = 0; ni < 4; ++ni) {
        int c = n0 + wc * 64 + ni * 16 + q16;
        out[(size_t)m * 1024 + c] = (acc[mi][ni][r] + bias[c]) * mm;
      }
    }
  }
}

// ---------------- flash attention: 4-wave blocks, QS=4, 4-buffer LDS ----------------
// (round-6 proven version; r7 lesson: the accL ONES-MFMA is load-bearing for
// regalloc -- replacing it with a VALU lsum chain spilled at the 128-VGPR wall.)
// grid (64 bh, 8 qchunks of 256 rows), 4 waves (256 thr), 64 q-rows/wave (QS=4).
// 4 buffers, 2-ahead prefetch, steady-state vmcnt(8) (never 0 in-loop).
// V is key-permuted in global (see gemm_qkv) so vf is ONE ds_read_b128/lane.
// Swapped QK^T (mfma(K,Q,C=bias)); PV key-perm (lane's own p IS its A-frag).
#define QS 4
__global__ __launch_bounds__(256, 2) void attn_kernel(
    const u16* __restrict__ qb, const u16* __restrict__ kb,
    const u16* __restrict__ vt, const float* __restrict__ maskBias,
    u16* __restrict__ aout) {
  __shared__ __align__(16) char Kl[32768];   // 4 x [64][64] u16
  __shared__ __align__(16) char Vl[32768];   // 4 x [64 d][64 k'] u16
  __shared__ __align__(16) float Bl[2048];   // bias row (exp2-domain)
  const int t = threadIdx.x;                 // 0..255
  const int wave = t >> 6, lane = t & 63;
  const int g = lane >> 4, q16 = lane & 15;
  const int bh = blockIdx.x;
  const int b = bh >> 4, h = bh & 15;
  const int qbase = blockIdx.y * 256 + wave * 64;

  const u16* Q = qb + (size_t)bh * (2048 * 64);
  const u16* K = kb + (size_t)bh * (2048 * 64);
  const u16* VT = vt + (size_t)bh * (64 * 2048);
  const float* mbp = maskBias + b * 2048;

  bf16x8 qf[QS][2];
#pragma unroll
  for (int qs = 0; qs < QS; ++qs)
#pragma unroll
    for (int hh = 0; hh < 2; ++hh)
      qf[qs][hh] = *(const bf16x8*)(Q + (size_t)(qbase + qs * 16 + q16) * 64 + hh * 32 + g * 8);

  us4 one4;
  one4[0] = one4[1] = one4[2] = one4[3] = 0x3f80;  // bf16 1.0
  const bf16x8 ONES = combine2us4(one4, one4);

  f32x4 acc[QS][4];
  f32x4 accL[QS];
#pragma unroll
  for (int i = 0; i < QS; ++i) {
#pragma unroll
    for (int j = 0; j < 4; ++j) acc[i][j] = (f32x4){0.f, 0.f, 0.f, 0.f};
    accL[i] = (f32x4){0.f, 0.f, 0.f, 0.f};
  }

  // staging geometry (256 threads cover a 64x64 u16 tile in 2 halves of 4KB)
  const int srow = t >> 3;                    // 0..31 (rows 0..31 / 32..63)
  const int sch = ((t & 7) ^ (srow & 7)) * 8; // swizzled source u16-offset

  auto stage = [&](int k0, int bsel) {        // k0 = key index of tile; 4 loads
    gload_lds16(K + (size_t)(k0 + srow) * 64 + sch,          Kl + bsel + wave * 1024);
    gload_lds16(K + (size_t)(k0 + 32 + srow) * 64 + sch,     Kl + bsel + 4096 + wave * 1024);
    gload_lds16(VT + (size_t)srow * 2048 + k0 + sch,         Vl + bsel + wave * 1024);
    gload_lds16(VT + (size_t)(32 + srow) * 2048 + k0 + sch,  Vl + bsel + 4096 + wave * 1024);
  };

  const int xsw = (q16 & 7);  // chunk XOR for this lane's rows (row&7 == q16&7)
  auto comp = [&](int k0, const char* ktl, const char* vtl) {
#pragma unroll
    for (int h2 = 0; h2 < 2; ++h2) {
      bf16x8 kf[2][2];
#pragma unroll
      for (int ks = 0; ks < 2; ++ks)
#pragma unroll
        for (int hh = 0; hh < 2; ++hh) {
          int r = h2 * 32 + ks * 16 + q16;
          int ch = (hh * 4 + g) ^ xsw;
          kf[ks][hh] = *(const bf16x8*)(ktl + r * 128 + ch * 16);
        }
      f32x4 blo = *(const f32x4*)(Bl + k0 + h2 * 32 + 4 * g);
      f32x4 bhi = *(const f32x4*)(Bl + k0 + h2 * 32 + 16 + 4 * g);
      bf16x8 vf[4];
#pragma unroll
      for (int dt = 0; dt < 4; ++dt) {
        // permuted V layout: lane's 8 B-frag keys are one contiguous chunk
        int rd = dt * 16 + q16;
        int ch = (h2 * 4 + g) ^ xsw;
        vf[dt] = *(const bf16x8*)(vtl + rd * 128 + ch * 16);
      }
      f32x4 s0[QS], s1[QS];
      __builtin_amdgcn_s_setprio(1);
#pragma unroll
      for (int qs = 0; qs < QS; ++qs) {
        s0[qs] = MFMA16(kf[0][0], qf[qs][0], blo);
        s0[qs] = MFMA16(kf[0][1], qf[qs][1], s0[qs]);
        s1[qs] = MFMA16(kf[1][0], qf[qs][0], bhi);
        s1[qs] = MFMA16(kf[1][1], qf[qs][1], s1[qs]);
      }
      __builtin_amdgcn_s_setprio(0);
#pragma unroll
      for (int qs = 0; qs < QS; ++qs) {
        float p[8];
#pragma unroll
        for (int r = 0; r < 4; ++r) {
          p[r] = exp2_fast(s0[qs][r]);
          p[4 + r] = exp2_fast(s1[qs][r]);
        }
        bf16x8 pa = combine4w(cvtpk_bf16(p[0], p[1]), cvtpk_bf16(p[2], p[3]),
                              cvtpk_bf16(p[4], p[5]), cvtpk_bf16(p[6], p[7]));
        __builtin_amdgcn_s_setprio(1);
#pragma unroll
        for (int dt = 0; dt < 4; ++dt) acc[qs][dt] = MFMA16(pa, vf[dt], acc[qs][dt]);
        accL[qs] = MFMA16(pa, ONES, accL[qs]);
        __builtin_amdgcn_s_setprio(0);
      }
    }
  };

#define PHASE_WAIT_BAR(N)                                \
  asm volatile("s_waitcnt vmcnt(" #N ")" ::: "memory");  \
  __builtin_amdgcn_s_barrier();                          \
  __builtin_amdgcn_sched_barrier(0);

  // prologue: bias (2 loads: 2x 256thr x 16B = 8KB) + tiles 0,1
  gload_lds16(mbp + t * 4,        (char*)Bl + wave * 1024);
  gload_lds16(mbp + 1024 + t * 4, (char*)Bl + 4096 + wave * 1024);
  stage(0, 0);
  stage(64, 8192);

#pragma unroll 1
  for (int tile = 0; tile < 28; tile += 4) {
    const int k0 = tile * 64;
    stage(k0 + 128, 16384); PHASE_WAIT_BAR(8) comp(k0,       Kl,         Vl);
    stage(k0 + 192, 24576); PHASE_WAIT_BAR(8) comp(k0 + 64,  Kl + 8192,  Vl + 8192);
    stage(k0 + 256, 0);     PHASE_WAIT_BAR(8) comp(k0 + 128, Kl + 16384, Vl + 16384);
    stage(k0 + 320, 8192);  PHASE_WAIT_BAR(8) comp(k0 + 192, Kl + 24576, Vl + 24576);
  }
  {
    const int k0 = 28 * 64;
    stage(k0 + 128, 16384); PHASE_WAIT_BAR(8) comp(k0,       Kl,         Vl);
    stage(k0 + 192, 24576); PHASE_WAIT_BAR(8) comp(k0 + 64,  Kl + 8192,  Vl + 8192);
    PHASE_WAIT_BAR(4) comp(k0 + 128, Kl + 16384, Vl + 16384);
    PHASE_WAIT_BAR(0) comp(k0 + 192, Kl + 24576, Vl + 24576);
  }
#undef PHASE_WAIT_BAR

#pragma unroll
  for (int qs = 0; qs < QS; ++qs) {
    float linv[4];
#pragma unroll
    for (int r = 0; r < 4; ++r) linv[r] = 1.0f / accL[qs][r];
#pragma unroll
    for (int dt = 0; dt < 4; ++dt)
#pragma unroll
      for (int r = 0; r < 4; ++r) {
        int n = qbase + qs * 16 + 4 * g + r;
        aout[((size_t)(b * 2048 + n)) * 1024 + h * 64 + dt * 16 + q16] =
            f2bf(acc[qs][dt][r] * linv[r]);
      }
  }
}

// ---------------- launch ----------------
extern "C" void kernel_launch(void* const* d_in, const int* in_sizes, int n_in,
                              void* d_out, int out_size, void* d_ws, size_t ws_size,
                              hipStream_t stream) {
  (void)in_sizes; (void)n_in; (void)out_size; (void)ws_size;
  const float* x = (const float*)d_in[0];
  const void* mask = d_in[1];
  const float* freqs = (const float*)d_in[2];
  const float* w_in = (const float*)d_in[3];
  const float* b_in = (const float*)d_in[4];
  const float* w_out = (const float*)d_in[5];
  const float* b_out = (const float*)d_in[6];
  float* out = (float*)d_out;
  char* ws = (char*)d_ws;

  float* maskBias = (float*)ws;                       // 8192 f32
  float* maskMul = (float*)(ws + (32 << 10));         // 8192 f32
  u16* w_in_b = (u16*)(ws + (64 << 10));              // 3072*1024
  u16* w_out_b = w_in_b + 3145728;                    // 1024*1024
  u16* xb = w_out_b + 1048576;                        // 8192*1024 (reused as attn_out)
  u16* qbuf = xb + 8388608;                           // [b][h][n][64]
  u16* kbuf = qbuf + 8388608;
  u16* vT = kbuf + 8388608;                           // [b][h][64][n'] (key-permuted)

  fused_prep_kernel<<<2048, 256, 0, stream>>>(x, w_in, w_out, mask,
                                              xb, w_in_b, w_out_b, maskBias, maskMul);
  gemm_qkv_kernel<<<dim3(24, 64), 256, 0, stream>>>(xb, w_in_b, b_in, freqs, qbuf, kbuf, vT);
  attn_kernel<<<dim3(64, 8), 256, 0, stream>>>(qbuf, kbuf, vT, maskBias, xb);
  gemm_out_kernel<<<dim3(8, 64), 256, 0, stream>>>(xb, w_out_b, b_out, maskMul, out);
}

// Round 10
// 163.849 us; speedup vs baseline: 1.0014x; 1.0014x over previous
//
#include <hip/hip_runtime.h>

typedef unsigned short u16;
typedef __bf16 bf16x8 __attribute__((ext_vector_type(8)));
typedef float f32x4 __attribute__((ext_vector_type(4)));
typedef unsigned short us4 __attribute__((ext_vector_type(4)));

#define MFMA16(a, b, c) __builtin_amdgcn_mfma_f32_16x16x32_bf16((a), (b), (c), 0, 0, 0)

__device__ __forceinline__ unsigned short f2bf(float f) {
  unsigned u = __builtin_bit_cast(unsigned, f);
  u += 0x7fffu + ((u >> 16) & 1u);
  return (unsigned short)(u >> 16);
}
__device__ __forceinline__ float bf2f(unsigned short s) {
  unsigned u = ((unsigned)s) << 16;
  return __builtin_bit_cast(float, u);
}
__device__ __forceinline__ unsigned cvtpk_bf16(float a, float b) {
  unsigned r;
  asm("v_cvt_pk_bf16_f32 %0, %1, %2" : "=v"(r) : "v"(a), "v"(b));
  return r;
}
__device__ __forceinline__ float exp2_fast(float x) {
  float r;
  asm("v_exp_f32 %0, %1" : "=v"(r) : "v"(x));
  return r;
}
__device__ __forceinline__ bf16x8 combine2us4(us4 lo, us4 hi) {
  union { us4 h[2]; bf16x8 v; } u;
  u.h[0] = lo; u.h[1] = hi;
  return u.v;
}
__device__ __forceinline__ bf16x8 combine4w(unsigned a, unsigned b, unsigned c, unsigned d) {
  union { unsigned w[4]; bf16x8 v; } u;
  u.w[0] = a; u.w[1] = b; u.w[2] = c; u.w[3] = d;
  return u.v;
}
__device__ __forceinline__ void gload_lds16(const void* g, void* l) {
  __builtin_amdgcn_global_load_lds(
      (__attribute__((address_space(1))) void*)(unsigned long long)g,
      (__attribute__((address_space(3))) void*)l, 16, 0, 0);
}

// softmax scale folded with log2(e):  (1/sqrt(64)) * log2(e)
#define QSCALE 0.1803368801111601f
// -1e9 * log2(e)  (mask bias directly in exp2 domain)
#define MBIAS_L2E -1.442695040e9f

// ---------------- fused prep: mask prep + all f32->bf16 conversions ----------
__global__ void fused_prep_kernel(
    const float* __restrict__ x, const float* __restrict__ w_in,
    const float* __restrict__ w_out, const void* __restrict__ mask,
    u16* __restrict__ xb, u16* __restrict__ w_in_b, u16* __restrict__ w_out_b,
    float* __restrict__ mbias, float* __restrict__ mmul) {
  int tid = blockIdx.x * 256 + threadIdx.x;
  if (blockIdx.x < 32) {
    int i = tid;  // 0..8191
    const int* m32 = (const int*)mask;
    const float* mf = (const float*)mask;
    const unsigned char* m8 = (const unsigned char*)mask;
    bool i32ok = true, f32ok = true;
    for (int s = 0; s < 64; ++s) {
      int idx = s * 29 + 1;
      int v = m32[idx];
      float f = mf[idx];
      i32ok = i32ok && (v == 0 || v == 1);
      f32ok = f32ok && (f == 0.0f || f == 1.0f);
    }
    int val;
    if (i32ok) val = m32[i];
    else if (f32ok) val = (mf[i] != 0.0f) ? 1 : 0;
    else val = m8[i] ? 1 : 0;
    mbias[i] = val ? 0.0f : MBIAS_L2E;
    mmul[i] = val ? 1.0f : 0.0f;
  }
  const int stride = 2048 * 256;
  for (int i = tid; i < 3145728; i += stride) {
    const float* src;
    u16* dst;
    int off;
    if (i < 2097152) { src = x; dst = xb; off = i; }
    else if (i < 2883584) { src = w_in; dst = w_in_b; off = i - 2097152; }
    else { src = w_out; dst = w_out_b; off = i - 2883584; }
    f32x4 v = ((const f32x4*)src)[off];
    us4 o;
    o[0] = f2bf(v[0]); o[1] = f2bf(v[1]); o[2] = f2bf(v[2]); o[3] = f2bf(v[3]);
    ((us4*)dst)[off] = o;
  }
}

// ---------------- 128x128x(K=1024) bf16 MFMA GEMM mainloop -------------------
// Double-buffered (2 x 32KB LDS) with counted waits, wait-own-then-barrier:
// per iter {stage(t+1) -> buf^1; vmcnt(8); barrier; comp(t); barrier}.
// Never vmcnt(0) in-loop (r6: removed the ~20% __syncthreads drain stall).
__device__ __forceinline__ void gemm128_mainloop(
    const u16* __restrict__ Ag, const u16* __restrict__ Bg,
    int m0, int n0, char* Ls, f32x4 (&acc)[4][4]) {
  const int t = threadIdx.x;
  const int wave = t >> 6, lane = t & 63;
  const int g = lane >> 4, q16 = lane & 15;
  const int wr = wave >> 1, wc = wave & 1;

#pragma unroll
  for (int i = 0; i < 4; ++i)
#pragma unroll
    for (int j = 0; j < 4; ++j) acc[i][j] = (f32x4){0.f, 0.f, 0.f, 0.f};

  auto stage = [&](int kt, int bsel) {  // 8 gload_lds per thread
#pragma unroll
    for (int i = 0; i < 4; ++i) {
      int c = i * 256 + t;
      int row = c >> 3;
      int gch = (c & 7) ^ (row & 7);
      gload_lds16(Ag + (size_t)(m0 + row) * 1024 + kt * 64 + gch * 8,
                  Ls + bsel + i * 4096 + wave * 1024);
    }
#pragma unroll
    for (int i = 0; i < 4; ++i) {
      int c = i * 256 + t;
      int row = c >> 3;
      int gch = (c & 7) ^ (row & 7);
      gload_lds16(Bg + (size_t)(n0 + row) * 1024 + kt * 64 + gch * 8,
                  Ls + bsel + 16384 + i * 4096 + wave * 1024);
    }
  };

  auto comp = [&](int bsel) {
    const char* As = Ls + bsel;
    const char* Bs = Ls + bsel + 16384;
#pragma unroll
    for (int ks = 0; ks < 2; ++ks) {
      bf16x8 af[4], bfr[4];
#pragma unroll
      for (int mi = 0; mi < 4; ++mi) {
        int row = wr * 64 + mi * 16 + q16;
        int ch = (ks * 4 + g) ^ (row & 7);
        af[mi] = *(const bf16x8*)(As + row * 128 + ch * 16);
      }
#pragma unroll
      for (int ni = 0; ni < 4; ++ni) {
        int row = wc * 64 + ni * 16 + q16;
        int ch = (ks * 4 + g) ^ (row & 7);
        bfr[ni] = *(const bf16x8*)(Bs + row * 128 + ch * 16);
      }
      __builtin_amdgcn_s_setprio(1);
#pragma unroll
      for (int mi = 0; mi < 4; ++mi)
#pragma unroll
        for (int ni = 0; ni < 4; ++ni)
          acc[mi][ni] = MFMA16(af[mi], bfr[ni], acc[mi][ni]);
      __builtin_amdgcn_s_setprio(0);
    }
  };

  stage(0, 0);
#pragma unroll 1
  for (int kt = 0; kt < 15; ++kt) {
    const int bsel = (kt & 1) << 15;
    stage(kt + 1, bsel ^ 32768);
    asm volatile("s_waitcnt vmcnt(8)" ::: "memory");
    __builtin_amdgcn_sched_barrier(0);
    __builtin_amdgcn_s_barrier();
    __builtin_amdgcn_sched_barrier(0);
    comp(bsel);
    __builtin_amdgcn_s_barrier();
    __builtin_amdgcn_sched_barrier(0);
  }
  asm volatile("s_waitcnt vmcnt(0)" ::: "memory");
  __builtin_amdgcn_sched_barrier(0);
  __builtin_amdgcn_s_barrier();
  __builtin_amdgcn_sched_barrier(0);
  comp(32768);  // kt = 15 -> buf 1
}

// XCD-chunked bijective block swizzle (nwg % 8 == 0): keeps same-A-panel
// blocks (same by) on one XCD's L2.
__device__ __forceinline__ void xcd_swizzle(int gx, int gy, int& bx, int& by) {
  int lin = blockIdx.x + gx * blockIdx.y;
  int cpx = (gx * gy) >> 3;
  int sw = (lin & 7) * cpx + (lin >> 3);
  bx = sw % gx;
  by = sw / gx;
}

// ---------------- GEMM1: qkv = x @ w_in^T + b_in (+ fused RoPE) --------------
// q pre-scaled by QSCALE; v written TRANSPOSED into vt[bh][d][n'] (packed us4,
// within-32-key permutation n' = (n&~31)|((n>>2)&3)<<3|((n>>4)&1)<<2).
// RoPE fused into the epilogue for head-0 waves (wave-uniform wc==0 &&
// (n0&1023)==0). Rotation pair (dd, dd+1) sits in adjacent lanes (lane^1),
// v' = v*cos(f) -/+ shfl_xor(v,1)*sin(f); commutes with QSCALE.
__global__ __launch_bounds__(256) void gemm_qkv_kernel(
    const u16* __restrict__ A, const u16* __restrict__ B, const float* __restrict__ bias,
    const float* __restrict__ freqs,
    u16* __restrict__ qb, u16* __restrict__ kb, u16* __restrict__ vt) {
  __shared__ __align__(16) char Ls[65536];
  int bx, by;
  xcd_swizzle(24, 64, bx, by);
  const int m0 = by * 128, n0 = bx * 128;
  f32x4 acc[4][4];
  gemm128_mainloop(A, B, m0, n0, Ls, acc);
  const int t = threadIdx.x, wave = t >> 6, lane = t & 63, g = lane >> 4, q16 = lane & 15;
  const int wr = wave >> 1, wc = wave & 1;
  const int seg = n0 >> 10;  // 0=q, 1=k, 2=v (uniform per block)
  if (seg < 2) {
    u16* dst = seg ? kb : qb;
    float sc = seg ? 1.0f : QSCALE;
    const bool ropeW = (wc == 0) && ((n0 & 1023) == 0);  // head-0 wave (uniform)
    if (ropeW) {
#pragma unroll
      for (int ni = 0; ni < 4; ++ni) {
        int c = n0 + ni * 16 + q16;        // wc == 0
        float bv = bias[c];
        int dd = c & 63;                   // head-0: dd == cc, hh == 0
#pragma unroll
        for (int mi = 0; mi < 4; ++mi) {
#pragma unroll
          for (int r = 0; r < 4; ++r) {
            int m = m0 + wr * 64 + mi * 16 + 4 * g + r;
            int bb = m >> 11, nn = m & 2047;
            float v = (acc[mi][ni][r] + bv) * sc;
            float vp = __shfl_xor(v, 1);
            float f = freqs[nn * 64 + dd];
            float sn, cs;
            __sincosf(f, &sn, &cs);
            float rot = (q16 & 1) ? (v * cs + vp * sn) : (v * cs - vp * sn);
            dst[((size_t)(bb * 16) * 2048 + nn) * 64 + dd] = f2bf(rot);
          }
        }
      }
    } else {
#pragma unroll
      for (int ni = 0; ni < 4; ++ni) {
        int c = n0 + wc * 64 + ni * 16 + q16;
        float bv = bias[c];
        int cc = c & 1023, hh = cc >> 6, dd = cc & 63;
#pragma unroll
        for (int mi = 0; mi < 4; ++mi) {
#pragma unroll
          for (int r = 0; r < 4; ++r) {
            int m = m0 + wr * 64 + mi * 16 + 4 * g + r;
            int bb = m >> 11, nn = m & 2047;
            dst[((size_t)(bb * 16 + hh) * 2048 + nn) * 64 + dd] =
                f2bf((acc[mi][ni][r] + bv) * sc);
          }
        }
      }
    }
  } else {
#pragma unroll
    for (int ni = 0; ni < 4; ++ni) {
      int c = n0 + wc * 64 + ni * 16 + q16;
      float bv = bias[c];
      int cc = c & 1023, hh = cc >> 6, dd = cc & 63;
#pragma unroll
      for (int mi = 0; mi < 4; ++mi) {
        int mbase = m0 + wr * 64 + mi * 16 + 4 * g;
        int bb = mbase >> 11, nn = mbase & 2047;
        // within-32 key permutation (bijective on us4 groups)
        int nnp = (nn & ~31) | (((nn >> 2) & 3) << 3) | (((nn >> 4) & 1) << 2);
        us4 pk;
#pragma unroll
        for (int r = 0; r < 4; ++r) pk[r] = f2bf(acc[mi][ni][r] + bv);
        *(us4*)(vt + ((size_t)((bb * 16 + hh) * 64 + dd)) * 2048 + nnp) = pk;
      }
    }
  }
}

// ---------------- GEMM3: out = attn_out @ w_out^T + b_out, * maskMul ----------------
__global__ __launch_bounds__(256) void gemm_out_kernel(
    const u16* __restrict__ A, const u16* __restrict__ B, const float* __restrict__ bias,
    const float* __restrict__ maskMul, float* __restrict__ out) {
  __shared__ __align__(16) char Ls[65536];
  int bx, by;
  xcd_swizzle(8, 64, bx, by);
  const int m0 = by * 128, n0 = bx * 128;
  f32x4 acc[4][4];
  gemm128_mainloop(A, B, m0, n0, Ls, acc);
  const int t = threadIdx.x, wave = t >> 6, lane = t & 63, g = lane >> 4, q16 = lane & 15;
  const int wr = wave >> 1, wc = wave & 1;
#pragma unroll
  for (int mi = 0; mi < 4; ++mi) {
#pragma unroll
    for (int r = 0; r < 4; ++r) {
      int m = m0 + wr * 64 + mi * 16 + 4 * g + r;
      float mm = maskMul[m];
#pragma unroll
      for (int ni = 0; ni < 4; ++ni) {
        int c = n0 + wc * 64 + ni * 16 + q16;
        out[(size_t)m * 1024 + c] = (acc[mi][ni][r] + bias[c]) * mm;
      }
    }
  }
}

// ---------------- flash attention: 4-wave blocks, QS=4, 4-buffer LDS ----------------
// (r6 structure; r7 lesson: accL ONES-MFMA is load-bearing for regalloc.)
// grid (64 bh, 8 qchunks of 256 rows), 4 waves (256 thr), 64 q-rows/wave (QS=4).
// 4 buffers, 2-ahead prefetch, steady-state vmcnt(8) (never 0 in-loop).
// V is key-permuted in global (see gemm_qkv) so vf is ONE ds_read_b128/lane.
// Swapped QK^T (mfma(K,Q,C=bias)); PV key-perm (lane's own p IS its A-frag).
// NEW (r10): comp restructured into role CLUSTERS per h2 -- {16 QK MFMA} ->
// {all-4-qs exp2+cvtpk VALU cluster} -> {all-4-qs PV+accL 20-MFMA cluster}.
// T5 mechanism: with 2 waves/SIMD (register-capped: 112V+80A=192), longer
// homogeneous clusters let wave A's MFMA cluster overlap wave B's VALU
// cluster instead of colliding per-qs (measured 28% dual-idle). Register
// delta +16V (pa[4] live across VALU cluster).
#define QS 4
__global__ __launch_bounds__(256, 2) void attn_kernel(
    const u16* __restrict__ qb, const u16* __restrict__ kb,
    const u16* __restrict__ vt, const float* __restrict__ maskBias,
    u16* __restrict__ aout) {
  __shared__ __align__(16) char Kl[32768];   // 4 x [64][64] u16
  __shared__ __align__(16) char Vl[32768];   // 4 x [64 d][64 k'] u16
  __shared__ __align__(16) float Bl[2048];   // bias row (exp2-domain)
  const int t = threadIdx.x;                 // 0..255
  const int wave = t >> 6, lane = t & 63;
  const int g = lane >> 4, q16 = lane & 15;
  const int bh = blockIdx.x;
  const int b = bh >> 4, h = bh & 15;
  const int qbase = blockIdx.y * 256 + wave * 64;

  const u16* Q = qb + (size_t)bh * (2048 * 64);
  const u16* K = kb + (size_t)bh * (2048 * 64);
  const u16* VT = vt + (size_t)bh * (64 * 2048);
  const float* mbp = maskBias + b * 2048;

  bf16x8 qf[QS][2];
#pragma unroll
  for (int qs = 0; qs < QS; ++qs)
#pragma unroll
    for (int hh = 0; hh < 2; ++hh)
      qf[qs][hh] = *(const bf16x8*)(Q + (size_t)(qbase + qs * 16 + q16) * 64 + hh * 32 + g * 8);

  us4 one4;
  one4[0] = one4[1] = one4[2] = one4[3] = 0x3f80;  // bf16 1.0
  const bf16x8 ONES = combine2us4(one4, one4);

  f32x4 acc[QS][4];
  f32x4 accL[QS];
#pragma unroll
  for (int i = 0; i < QS; ++i) {
#pragma unroll
    for (int j = 0; j < 4; ++j) acc[i][j] = (f32x4){0.f, 0.f, 0.f, 0.f};
    accL[i] = (f32x4){0.f, 0.f, 0.f, 0.f};
  }

  // staging geometry (256 threads cover a 64x64 u16 tile in 2 halves of 4KB)
  const int srow = t >> 3;                    // 0..31 (rows 0..31 / 32..63)
  const int sch = ((t & 7) ^ (srow & 7)) * 8; // swizzled source u16-offset

  auto stage = [&](int k0, int bsel) {        // k0 = key index of tile; 4 loads
    gload_lds16(K + (size_t)(k0 + srow) * 64 + sch,          Kl + bsel + wave * 1024);
    gload_lds16(K + (size_t)(k0 + 32 + srow) * 64 + sch,     Kl + bsel + 4096 + wave * 1024);
    gload_lds16(VT + (size_t)srow * 2048 + k0 + sch,         Vl + bsel + wave * 1024);
    gload_lds16(VT + (size_t)(32 + srow) * 2048 + k0 + sch,  Vl + bsel + 4096 + wave * 1024);
  };

  const int xsw = (q16 & 7);  // chunk XOR for this lane's rows (row&7 == q16&7)
  auto comp = [&](int k0, const char* ktl, const char* vtl) {
#pragma unroll
    for (int h2 = 0; h2 < 2; ++h2) {
      bf16x8 kf[2][2];
#pragma unroll
      for (int ks = 0; ks < 2; ++ks)
#pragma unroll
        for (int hh = 0; hh < 2; ++hh) {
          int r = h2 * 32 + ks * 16 + q16;
          int ch = (hh * 4 + g) ^ xsw;
          kf[ks][hh] = *(const bf16x8*)(ktl + r * 128 + ch * 16);
        }
      f32x4 blo = *(const f32x4*)(Bl + k0 + h2 * 32 + 4 * g);
      f32x4 bhi = *(const f32x4*)(Bl + k0 + h2 * 32 + 16 + 4 * g);
      bf16x8 vf[4];
#pragma unroll
      for (int dt = 0; dt < 4; ++dt) {
        // permuted V layout: lane's 8 B-frag keys are one contiguous chunk
        int rd = dt * 16 + q16;
        int ch = (h2 * 4 + g) ^ xsw;
        vf[dt] = *(const bf16x8*)(vtl + rd * 128 + ch * 16);
      }
      // MFMA cluster 1: all QK^T (16 MFMA)
      f32x4 s0[QS], s1[QS];
      __builtin_amdgcn_s_setprio(1);
#pragma unroll
      for (int qs = 0; qs < QS; ++qs) {
        s0[qs] = MFMA16(kf[0][0], qf[qs][0], blo);
        s0[qs] = MFMA16(kf[0][1], qf[qs][1], s0[qs]);
        s1[qs] = MFMA16(kf[1][0], qf[qs][0], bhi);
        s1[qs] = MFMA16(kf[1][1], qf[qs][1], s1[qs]);
      }
      __builtin_amdgcn_s_setprio(0);
      // VALU cluster: softmax exp + pack for ALL qs (low prio: yield MFMA
      // pipe to the co-resident wave's MFMA cluster)
      bf16x8 pa[QS];
#pragma unroll
      for (int qs = 0; qs < QS; ++qs) {
        float p[8];
#pragma unroll
        for (int r = 0; r < 4; ++r) {
          p[r] = exp2_fast(s0[qs][r]);
          p[4 + r] = exp2_fast(s1[qs][r]);
        }
        pa[qs] = combine4w(cvtpk_bf16(p[0], p[1]), cvtpk_bf16(p[2], p[3]),
                           cvtpk_bf16(p[4], p[5]), cvtpk_bf16(p[6], p[7]));
      }
      // MFMA cluster 2: PV + l-sum for ALL qs (20 MFMA)
      __builtin_amdgcn_s_setprio(1);
#pragma unroll
      for (int qs = 0; qs < QS; ++qs) {
#pragma unroll
        for (int dt = 0; dt < 4; ++dt) acc[qs][dt] = MFMA16(pa[qs], vf[dt], acc[qs][dt]);
        accL[qs] = MFMA16(pa[qs], ONES, accL[qs]);
      }
      __builtin_amdgcn_s_setprio(0);
    }
  };

#define PHASE_WAIT_BAR(N)                                \
  asm volatile("s_waitcnt vmcnt(" #N ")" ::: "memory");  \
  __builtin_amdgcn_s_barrier();                          \
  __builtin_amdgcn_sched_barrier(0);

  // prologue: bias (2 loads: 2x 256thr x 16B = 8KB) + tiles 0,1
  gload_lds16(mbp + t * 4,        (char*)Bl + wave * 1024);
  gload_lds16(mbp + 1024 + t * 4, (char*)Bl + 4096 + wave * 1024);
  stage(0, 0);
  stage(64, 8192);

#pragma unroll 1
  for (int tile = 0; tile < 28; tile += 4) {
    const int k0 = tile * 64;
    stage(k0 + 128, 16384); PHASE_WAIT_BAR(8) comp(k0,       Kl,         Vl);
    stage(k0 + 192, 24576); PHASE_WAIT_BAR(8) comp(k0 + 64,  Kl + 8192,  Vl + 8192);
    stage(k0 + 256, 0);     PHASE_WAIT_BAR(8) comp(k0 + 128, Kl + 16384, Vl + 16384);
    stage(k0 + 320, 8192);  PHASE_WAIT_BAR(8) comp(k0 + 192, Kl + 24576, Vl + 24576);
  }
  {
    const int k0 = 28 * 64;
    stage(k0 + 128, 16384); PHASE_WAIT_BAR(8) comp(k0,       Kl,         Vl);
    stage(k0 + 192, 24576); PHASE_WAIT_BAR(8) comp(k0 + 64,  Kl + 8192,  Vl + 8192);
    PHASE_WAIT_BAR(4) comp(k0 + 128, Kl + 16384, Vl + 16384);
    PHASE_WAIT_BAR(0) comp(k0 + 192, Kl + 24576, Vl + 24576);
  }
#undef PHASE_WAIT_BAR

#pragma unroll
  for (int qs = 0; qs < QS; ++qs) {
    float linv[4];
#pragma unroll
    for (int r = 0; r < 4; ++r) linv[r] = 1.0f / accL[qs][r];
#pragma unroll
    for (int dt = 0; dt < 4; ++dt)
#pragma unroll
      for (int r = 0; r < 4; ++r) {
        int n = qbase + qs * 16 + 4 * g + r;
        aout[((size_t)(b * 2048 + n)) * 1024 + h * 64 + dt * 16 + q16] =
            f2bf(acc[qs][dt][r] * linv[r]);
      }
  }
}

// ---------------- launch ----------------
extern "C" void kernel_launch(void* const* d_in, const int* in_sizes, int n_in,
                              void* d_out, int out_size, void* d_ws, size_t ws_size,
                              hipStream_t stream) {
  (void)in_sizes; (void)n_in; (void)out_size; (void)ws_size;
  const float* x = (const float*)d_in[0];
  const void* mask = d_in[1];
  const float* freqs = (const float*)d_in[2];
  const float* w_in = (const float*)d_in[3];
  const float* b_in = (const float*)d_in[4];
  const float* w_out = (const float*)d_in[5];
  const float* b_out = (const float*)d_in[6];
  float* out = (float*)d_out;
  char* ws = (char*)d_ws;

  float* maskBias = (float*)ws;                       // 8192 f32
  float* maskMul = (float*)(ws + (32 << 10));         // 8192 f32
  u16* w_in_b = (u16*)(ws + (64 << 10));              // 3072*1024
  u16* w_out_b = w_in_b + 3145728;                    // 1024*1024
  u16* xb = w_out_b + 1048576;                        // 8192*1024 (reused as attn_out)
  u16* qbuf = xb + 8388608;                           // [b][h][n][64]
  u16* kbuf = qbuf + 8388608;
  u16* vT = kbuf + 8388608;                           // [b][h][64][n'] (key-permuted)

  fused_prep_kernel<<<2048, 256, 0, stream>>>(x, w_in, w_out, mask,
                                              xb, w_in_b, w_out_b, maskBias, maskMul);
  gemm_qkv_kernel<<<dim3(24, 64), 256, 0, stream>>>(xb, w_in_b, b_in, freqs, qbuf, kbuf, vT);
  attn_kernel<<<dim3(64, 8), 256, 0, stream>>>(qbuf, kbuf, vT, maskBias, xb);
  gemm_out_kernel<<<dim3(8, 64), 256, 0, stream>>>(xb, w_out_b, b_out, maskMul, out);
}

// Round 11
// 162.934 us; speedup vs baseline: 1.0071x; 1.0056x over previous
//
#include <hip/hip_runtime.h>

typedef unsigned short u16;
typedef __bf16 bf16x8 __attribute__((ext_vector_type(8)));
typedef float f32x4 __attribute__((ext_vector_type(4)));
typedef unsigned short us4 __attribute__((ext_vector_type(4)));

#define MFMA16(a, b, c) __builtin_amdgcn_mfma_f32_16x16x32_bf16((a), (b), (c), 0, 0, 0)

__device__ __forceinline__ unsigned short f2bf(float f) {
  unsigned u = __builtin_bit_cast(unsigned, f);
  u += 0x7fffu + ((u >> 16) & 1u);
  return (unsigned short)(u >> 16);
}
__device__ __forceinline__ float bf2f(unsigned short s) {
  unsigned u = ((unsigned)s) << 16;
  return __builtin_bit_cast(float, u);
}
__device__ __forceinline__ unsigned cvtpk_bf16(float a, float b) {
  unsigned r;
  asm("v_cvt_pk_bf16_f32 %0, %1, %2" : "=v"(r) : "v"(a), "v"(b));
  return r;
}
__device__ __forceinline__ float exp2_fast(float x) {
  float r;
  asm("v_exp_f32 %0, %1" : "=v"(r) : "v"(x));
  return r;
}
__device__ __forceinline__ bf16x8 combine2us4(us4 lo, us4 hi) {
  union { us4 h[2]; bf16x8 v; } u;
  u.h[0] = lo; u.h[1] = hi;
  return u.v;
}
__device__ __forceinline__ bf16x8 combine4w(unsigned a, unsigned b, unsigned c, unsigned d) {
  union { unsigned w[4]; bf16x8 v; } u;
  u.w[0] = a; u.w[1] = b; u.w[2] = c; u.w[3] = d;
  return u.v;
}
__device__ __forceinline__ void gload_lds16(const void* g, void* l) {
  __builtin_amdgcn_global_load_lds(
      (__attribute__((address_space(1))) void*)(unsigned long long)g,
      (__attribute__((address_space(3))) void*)l, 16, 0, 0);
}

// softmax scale folded with log2(e):  (1/sqrt(64)) * log2(e)
#define QSCALE 0.1803368801111601f
// -1e9 * log2(e)  (mask bias directly in exp2 domain)
#define MBIAS_L2E -1.442695040e9f

// ---------------- fused prep: mask prep + all f32->bf16 conversions ----------
// Replaces 4 launches (prep_mask + 3x cvt) with one. Blocks 0..31 additionally
// handle the 8192-entry mask (dtype detection as before). Grid-stride cvt over
// the concatenated x (2097152 f32x4), w_in (786432), w_out (262144) segments.
__global__ void fused_prep_kernel(
    const float* __restrict__ x, const float* __restrict__ w_in,
    const float* __restrict__ w_out, const void* __restrict__ mask,
    u16* __restrict__ xb, u16* __restrict__ w_in_b, u16* __restrict__ w_out_b,
    float* __restrict__ mbias, float* __restrict__ mmul) {
  int tid = blockIdx.x * 256 + threadIdx.x;
  if (blockIdx.x < 32) {
    int i = tid;  // 0..8191
    const int* m32 = (const int*)mask;
    const float* mf = (const float*)mask;
    const unsigned char* m8 = (const unsigned char*)mask;
    bool i32ok = true, f32ok = true;
    for (int s = 0; s < 64; ++s) {
      int idx = s * 29 + 1;
      int v = m32[idx];
      float f = mf[idx];
      i32ok = i32ok && (v == 0 || v == 1);
      f32ok = f32ok && (f == 0.0f || f == 1.0f);
    }
    int val;
    if (i32ok) val = m32[i];
    else if (f32ok) val = (mf[i] != 0.0f) ? 1 : 0;
    else val = m8[i] ? 1 : 0;
    mbias[i] = val ? 0.0f : MBIAS_L2E;
    mmul[i] = val ? 1.0f : 0.0f;
  }
  const int stride = 2048 * 256;
  for (int i = tid; i < 3145728; i += stride) {
    const float* src;
    u16* dst;
    int off;
    if (i < 2097152) { src = x; dst = xb; off = i; }
    else if (i < 2883584) { src = w_in; dst = w_in_b; off = i - 2097152; }
    else { src = w_out; dst = w_out_b; off = i - 2883584; }
    f32x4 v = ((const f32x4*)src)[off];
    us4 o;
    o[0] = f2bf(v[0]); o[1] = f2bf(v[1]); o[2] = f2bf(v[2]); o[3] = f2bf(v[3]);
    ((us4*)dst)[off] = o;
  }
}

// ---------------- 128x128x(K=1024) bf16 MFMA GEMM mainloop -------------------
// Double-buffered (2 x 32KB LDS) with counted waits, wait-own-then-barrier:
// per iter {stage(t+1) -> buf^1; vmcnt(8); barrier; comp(t); barrier}.
// Never vmcnt(0) in-loop (r6: removed the ~20% __syncthreads drain stall).
// Ledger: outstanding at wait = stage(t) 8 + stage(t+1) 8 = 16 -> vmcnt(8)
// drains exactly stage(t), for EVERY wave, BEFORE the barrier. Buffer
// overwrite safe: stage(t+1) issued after the trailing barrier of iter t-1.
__device__ __forceinline__ void gemm128_mainloop(
    const u16* __restrict__ Ag, const u16* __restrict__ Bg,
    int m0, int n0, char* Ls, f32x4 (&acc)[4][4]) {
  const int t = threadIdx.x;
  const int wave = t >> 6, lane = t & 63;
  const int g = lane >> 4, q16 = lane & 15;
  const int wr = wave >> 1, wc = wave & 1;

#pragma unroll
  for (int i = 0; i < 4; ++i)
#pragma unroll
    for (int j = 0; j < 4; ++j) acc[i][j] = (f32x4){0.f, 0.f, 0.f, 0.f};

  auto stage = [&](int kt, int bsel) {  // 8 gload_lds per thread
#pragma unroll
    for (int i = 0; i < 4; ++i) {
      int c = i * 256 + t;
      int row = c >> 3;
      int gch = (c & 7) ^ (row & 7);
      gload_lds16(Ag + (size_t)(m0 + row) * 1024 + kt * 64 + gch * 8,
                  Ls + bsel + i * 4096 + wave * 1024);
    }
#pragma unroll
    for (int i = 0; i < 4; ++i) {
      int c = i * 256 + t;
      int row = c >> 3;
      int gch = (c & 7) ^ (row & 7);
      gload_lds16(Bg + (size_t)(n0 + row) * 1024 + kt * 64 + gch * 8,
                  Ls + bsel + 16384 + i * 4096 + wave * 1024);
    }
  };

  auto comp = [&](int bsel) {
    const char* As = Ls + bsel;
    const char* Bs = Ls + bsel + 16384;
#pragma unroll
    for (int ks = 0; ks < 2; ++ks) {
      bf16x8 af[4], bfr[4];
#pragma unroll
      for (int mi = 0; mi < 4; ++mi) {
        int row = wr * 64 + mi * 16 + q16;
        int ch = (ks * 4 + g) ^ (row & 7);
        af[mi] = *(const bf16x8*)(As + row * 128 + ch * 16);
      }
#pragma unroll
      for (int ni = 0; ni < 4; ++ni) {
        int row = wc * 64 + ni * 16 + q16;
        int ch = (ks * 4 + g) ^ (row & 7);
        bfr[ni] = *(const bf16x8*)(Bs + row * 128 + ch * 16);
      }
      __builtin_amdgcn_s_setprio(1);
#pragma unroll
      for (int mi = 0; mi < 4; ++mi)
#pragma unroll
        for (int ni = 0; ni < 4; ++ni)
          acc[mi][ni] = MFMA16(af[mi], bfr[ni], acc[mi][ni]);
      __builtin_amdgcn_s_setprio(0);
    }
  };

  stage(0, 0);
#pragma unroll 1
  for (int kt = 0; kt < 15; ++kt) {
    const int bsel = (kt & 1) << 15;
    stage(kt + 1, bsel ^ 32768);
    asm volatile("s_waitcnt vmcnt(8)" ::: "memory");
    __builtin_amdgcn_sched_barrier(0);
    __builtin_amdgcn_s_barrier();
    __builtin_amdgcn_sched_barrier(0);
    comp(bsel);
    __builtin_amdgcn_s_barrier();
    __builtin_amdgcn_sched_barrier(0);
  }
  asm volatile("s_waitcnt vmcnt(0)" ::: "memory");
  __builtin_amdgcn_sched_barrier(0);
  __builtin_amdgcn_s_barrier();
  __builtin_amdgcn_sched_barrier(0);
  comp(32768);  // kt = 15 -> buf 1
}

// XCD-chunked bijective block swizzle (nwg % 8 == 0): keeps same-A-panel
// blocks (same by) on one XCD's L2. (Checked r10: alternative orientations
// model to the same ~140-150MB L2-miss traffic -- geometry-bound, keep.)
__device__ __forceinline__ void xcd_swizzle(int gx, int gy, int& bx, int& by) {
  int lin = blockIdx.x + gx * blockIdx.y;
  int cpx = (gx * gy) >> 3;
  int sw = (lin & 7) * cpx + (lin >> 3);
  bx = sw % gx;
  by = sw / gx;
}

// ---------------- GEMM1: qkv = x @ w_in^T + b_in ----------------
// q pre-scaled by QSCALE; v written TRANSPOSED into vt[bh][d][n'] (packed us4,
// within-32-key permutation n' = (n&~31)|((n>>2)&3)<<3|((n>>4)&1)<<2).
__global__ __launch_bounds__(256) void gemm_qkv_kernel(
    const u16* __restrict__ A, const u16* __restrict__ B, const float* __restrict__ bias,
    u16* __restrict__ qb, u16* __restrict__ kb, u16* __restrict__ vt) {
  __shared__ __align__(16) char Ls[65536];
  int bx, by;
  xcd_swizzle(24, 64, bx, by);
  const int m0 = by * 128, n0 = bx * 128;
  f32x4 acc[4][4];
  gemm128_mainloop(A, B, m0, n0, Ls, acc);
  const int t = threadIdx.x, wave = t >> 6, lane = t & 63, g = lane >> 4, q16 = lane & 15;
  const int wr = wave >> 1, wc = wave & 1;
  const int seg = n0 >> 10;  // 0=q, 1=k, 2=v (uniform per block)
  if (seg < 2) {
    u16* dst = seg ? kb : qb;
    float sc = seg ? 1.0f : QSCALE;
#pragma unroll
    for (int ni = 0; ni < 4; ++ni) {
      int c = n0 + wc * 64 + ni * 16 + q16;
      float bv = bias[c];
      int cc = c & 1023, hh = cc >> 6, dd = cc & 63;
#pragma unroll
      for (int mi = 0; mi < 4; ++mi) {
#pragma unroll
        for (int r = 0; r < 4; ++r) {
          int m = m0 + wr * 64 + mi * 16 + 4 * g + r;
          int bb = m >> 11, nn = m & 2047;
          dst[((size_t)(bb * 16 + hh) * 2048 + nn) * 64 + dd] = f2bf((acc[mi][ni][r] + bv) * sc);
        }
      }
    }
  } else {
#pragma unroll
    for (int ni = 0; ni < 4; ++ni) {
      int c = n0 + wc * 64 + ni * 16 + q16;
      float bv = bias[c];
      int cc = c & 1023, hh = cc >> 6, dd = cc & 63;
#pragma unroll
      for (int mi = 0; mi < 4; ++mi) {
        int mbase = m0 + wr * 64 + mi * 16 + 4 * g;
        int bb = mbase >> 11, nn = mbase & 2047;
        // within-32 key permutation (bijective on us4 groups)
        int nnp = (nn & ~31) | (((nn >> 2) & 3) << 3) | (((nn >> 4) & 1) << 2);
        us4 pk;
#pragma unroll
        for (int r = 0; r < 4; ++r) pk[r] = f2bf(acc[mi][ni][r] + bv);
        *(us4*)(vt + ((size_t)((bb * 16 + hh) * 64 + dd)) * 2048 + nnp) = pk;
      }
    }
  }
}

// ---------------- GEMM3: out = attn_out @ w_out^T + b_out, * maskMul ----------------
__global__ __launch_bounds__(256) void gemm_out_kernel(
    const u16* __restrict__ A, const u16* __restrict__ B, const float* __restrict__ bias,
    const float* __restrict__ maskMul, float* __restrict__ out) {
  __shared__ __align__(16) char Ls[65536];
  int bx, by;
  xcd_swizzle(8, 64, bx, by);
  const int m0 = by * 128, n0 = bx * 128;
  f32x4 acc[4][4];
  gemm128_mainloop(A, B, m0, n0, Ls, acc);
  const int t = threadIdx.x, wave = t >> 6, lane = t & 63, g = lane >> 4, q16 = lane & 15;
  const int wr = wave >> 1, wc = wave & 1;
#pragma unroll
  for (int mi = 0; mi < 4; ++mi) {
#pragma unroll
    for (int r = 0; r < 4; ++r) {
      int m = m0 + wr * 64 + mi * 16 + 4 * g + r;
      float mm = maskMul[m];
#pragma unroll
      for (int ni = 0; ni < 4; ++ni) {
        int c = n0 + wc * 64 + ni * 16 + q16;
        out[(size_t)m * 1024 + c] = (acc[mi][ni][r] + bias[c]) * mm;
      }
    }
  }
}

// ---------------- RoPE on the first 64 channels (head 0) of q and k ----------------
// Kept as a separate kernel: the r9 epilogue fusion measured +0.5us (noise,
// not a win) -- this configuration is the measured session best.
__global__ void rope_kernel(u16* __restrict__ qb, u16* __restrict__ kb,
                            const float* __restrict__ freqs) {
  int t = blockIdx.x * 256 + threadIdx.x;  // 0..262143
  int token = t >> 5, pr = t & 31;
  int b = token >> 11, n = token & 2047;
  size_t base = ((size_t)(b * 16 + 0) * 2048 + n) * 64 + pr * 2;
  float f0 = freqs[n * 64 + pr * 2], f1 = freqs[n * 64 + pr * 2 + 1];
  float s0, c0, s1, c1;
  __sincosf(f0, &s0, &c0);
  __sincosf(f1, &s1, &c1);
  {
    float x0 = bf2f(qb[base]), x1 = bf2f(qb[base + 1]);
    qb[base] = f2bf(x0 * c0 - x1 * s0);
    qb[base + 1] = f2bf(x1 * c1 + x0 * s1);
  }
  {
    float x0 = bf2f(kb[base]), x1 = bf2f(kb[base + 1]);
    kb[base] = f2bf(x0 * c0 - x1 * s0);
    kb[base + 1] = f2bf(x1 * c1 + x0 * s1);
  }
}

// ---------------- flash attention: 4-wave blocks, QS=4, 4-buffer LDS ----------------
// (r6/r8-proven version -- session-best config at 163.6us, 954 TF = the
// documented plain-HIP attention ladder endpoint.)
// r7 lesson: accL ONES-MFMA is load-bearing for regalloc (VALU lsum spilled).
// r10 lesson: role-cluster restructure is neutral -- compiler already
// achieves the MFMA/VALU overlap; structure-bound at 2 waves/SIMD
// (112 VGPR + 80 AGPR register cap).
// grid (64 bh, 8 qchunks of 256 rows), 4 waves (256 thr), 64 q-rows/wave (QS=4).
// 4 buffers, 2-ahead prefetch, steady-state vmcnt(8) (never 0 in-loop).
// V is key-permuted in global (see gemm_qkv) so vf is ONE ds_read_b128/lane.
// Swapped QK^T (mfma(K,Q,C=bias)); PV key-perm (lane's own p IS its A-frag).
#define QS 4
__global__ __launch_bounds__(256, 2) void attn_kernel(
    const u16* __restrict__ qb, const u16* __restrict__ kb,
    const u16* __restrict__ vt, const float* __restrict__ maskBias,
    u16* __restrict__ aout) {
  __shared__ __align__(16) char Kl[32768];   // 4 x [64][64] u16
  __shared__ __align__(16) char Vl[32768];   // 4 x [64 d][64 k'] u16
  __shared__ __align__(16) float Bl[2048];   // bias row (exp2-domain)
  const int t = threadIdx.x;                 // 0..255
  const int wave = t >> 6, lane = t & 63;
  const int g = lane >> 4, q16 = lane & 15;
  const int bh = blockIdx.x;
  const int b = bh >> 4, h = bh & 15;
  const int qbase = blockIdx.y * 256 + wave * 64;

  const u16* Q = qb + (size_t)bh * (2048 * 64);
  const u16* K = kb + (size_t)bh * (2048 * 64);
  const u16* VT = vt + (size_t)bh * (64 * 2048);
  const float* mbp = maskBias + b * 2048;

  bf16x8 qf[QS][2];
#pragma unroll
  for (int qs = 0; qs < QS; ++qs)
#pragma unroll
    for (int hh = 0; hh < 2; ++hh)
      qf[qs][hh] = *(const bf16x8*)(Q + (size_t)(qbase + qs * 16 + q16) * 64 + hh * 32 + g * 8);

  us4 one4;
  one4[0] = one4[1] = one4[2] = one4[3] = 0x3f80;  // bf16 1.0
  const bf16x8 ONES = combine2us4(one4, one4);

  f32x4 acc[QS][4];
  f32x4 accL[QS];
#pragma unroll
  for (int i = 0; i < QS; ++i) {
#pragma unroll
    for (int j = 0; j < 4; ++j) acc[i][j] = (f32x4){0.f, 0.f, 0.f, 0.f};
    accL[i] = (f32x4){0.f, 0.f, 0.f, 0.f};
  }

  // staging geometry (256 threads cover a 64x64 u16 tile in 2 halves of 4KB)
  const int srow = t >> 3;                    // 0..31 (rows 0..31 / 32..63)
  const int sch = ((t & 7) ^ (srow & 7)) * 8; // swizzled source u16-offset

  auto stage = [&](int k0, int bsel) {        // k0 = key index of tile; 4 loads
    gload_lds16(K + (size_t)(k0 + srow) * 64 + sch,          Kl + bsel + wave * 1024);
    gload_lds16(K + (size_t)(k0 + 32 + srow) * 64 + sch,     Kl + bsel + 4096 + wave * 1024);
    gload_lds16(VT + (size_t)srow * 2048 + k0 + sch,         Vl + bsel + wave * 1024);
    gload_lds16(VT + (size_t)(32 + srow) * 2048 + k0 + sch,  Vl + bsel + 4096 + wave * 1024);
  };

  const int xsw = (q16 & 7);  // chunk XOR for this lane's rows (row&7 == q16&7)
  auto comp = [&](int k0, const char* ktl, const char* vtl) {
#pragma unroll
    for (int h2 = 0; h2 < 2; ++h2) {
      bf16x8 kf[2][2];
#pragma unroll
      for (int ks = 0; ks < 2; ++ks)
#pragma unroll
        for (int hh = 0; hh < 2; ++hh) {
          int r = h2 * 32 + ks * 16 + q16;
          int ch = (hh * 4 + g) ^ xsw;
          kf[ks][hh] = *(const bf16x8*)(ktl + r * 128 + ch * 16);
        }
      f32x4 blo = *(const f32x4*)(Bl + k0 + h2 * 32 + 4 * g);
      f32x4 bhi = *(const f32x4*)(Bl + k0 + h2 * 32 + 16 + 4 * g);
      bf16x8 vf[4];
#pragma unroll
      for (int dt = 0; dt < 4; ++dt) {
        // permuted V layout: lane's 8 B-frag keys are one contiguous chunk
        int rd = dt * 16 + q16;
        int ch = (h2 * 4 + g) ^ xsw;
        vf[dt] = *(const bf16x8*)(vtl + rd * 128 + ch * 16);
      }
      f32x4 s0[QS], s1[QS];
      __builtin_amdgcn_s_setprio(1);
#pragma unroll
      for (int qs = 0; qs < QS; ++qs) {
        s0[qs] = MFMA16(kf[0][0], qf[qs][0], blo);
        s0[qs] = MFMA16(kf[0][1], qf[qs][1], s0[qs]);
        s1[qs] = MFMA16(kf[1][0], qf[qs][0], bhi);
        s1[qs] = MFMA16(kf[1][1], qf[qs][1], s1[qs]);
      }
      __builtin_amdgcn_s_setprio(0);
#pragma unroll
      for (int qs = 0; qs < QS; ++qs) {
        float p[8];
#pragma unroll
        for (int r = 0; r < 4; ++r) {
          p[r] = exp2_fast(s0[qs][r]);
          p[4 + r] = exp2_fast(s1[qs][r]);
        }
        bf16x8 pa = combine4w(cvtpk_bf16(p[0], p[1]), cvtpk_bf16(p[2], p[3]),
                              cvtpk_bf16(p[4], p[5]), cvtpk_bf16(p[6], p[7]));
        __builtin_amdgcn_s_setprio(1);
#pragma unroll
        for (int dt = 0; dt < 4; ++dt) acc[qs][dt] = MFMA16(pa, vf[dt], acc[qs][dt]);
        accL[qs] = MFMA16(pa, ONES, accL[qs]);
        __builtin_amdgcn_s_setprio(0);
      }
    }
  };

#define PHASE_WAIT_BAR(N)                                \
  asm volatile("s_waitcnt vmcnt(" #N ")" ::: "memory");  \
  __builtin_amdgcn_s_barrier();                          \
  __builtin_amdgcn_sched_barrier(0);

  // prologue: bias (2 loads: 2x 256thr x 16B = 8KB) + tiles 0,1
  gload_lds16(mbp + t * 4,        (char*)Bl + wave * 1024);
  gload_lds16(mbp + 1024 + t * 4, (char*)Bl + 4096 + wave * 1024);
  stage(0, 0);
  stage(64, 8192);

#pragma unroll 1
  for (int tile = 0; tile < 28; tile += 4) {
    const int k0 = tile * 64;
    stage(k0 + 128, 16384); PHASE_WAIT_BAR(8) comp(k0,       Kl,         Vl);
    stage(k0 + 192, 24576); PHASE_WAIT_BAR(8) comp(k0 + 64,  Kl + 8192,  Vl + 8192);
    stage(k0 + 256, 0);     PHASE_WAIT_BAR(8) comp(k0 + 128, Kl + 16384, Vl + 16384);
    stage(k0 + 320, 8192);  PHASE_WAIT_BAR(8) comp(k0 + 192, Kl + 24576, Vl + 24576);
  }
  {
    const int k0 = 28 * 64;
    stage(k0 + 128, 16384); PHASE_WAIT_BAR(8) comp(k0,       Kl,         Vl);
    stage(k0 + 192, 24576); PHASE_WAIT_BAR(8) comp(k0 + 64,  Kl + 8192,  Vl + 8192);
    PHASE_WAIT_BAR(4) comp(k0 + 128, Kl + 16384, Vl + 16384);
    PHASE_WAIT_BAR(0) comp(k0 + 192, Kl + 24576, Vl + 24576);
  }
#undef PHASE_WAIT_BAR

#pragma unroll
  for (int qs = 0; qs < QS; ++qs) {
    float linv[4];
#pragma unroll
    for (int r = 0; r < 4; ++r) linv[r] = 1.0f / accL[qs][r];
#pragma unroll
    for (int dt = 0; dt < 4; ++dt)
#pragma unroll
      for (int r = 0; r < 4; ++r) {
        int n = qbase + qs * 16 + 4 * g + r;
        aout[((size_t)(b * 2048 + n)) * 1024 + h * 64 + dt * 16 + q16] =
            f2bf(acc[qs][dt][r] * linv[r]);
      }
  }
}

// ---------------- launch ----------------
extern "C" void kernel_launch(void* const* d_in, const int* in_sizes, int n_in,
                              void* d_out, int out_size, void* d_ws, size_t ws_size,
                              hipStream_t stream) {
  (void)in_sizes; (void)n_in; (void)out_size; (void)ws_size;
  const float* x = (const float*)d_in[0];
  const void* mask = d_in[1];
  const float* freqs = (const float*)d_in[2];
  const float* w_in = (const float*)d_in[3];
  const float* b_in = (const float*)d_in[4];
  const float* w_out = (const float*)d_in[5];
  const float* b_out = (const float*)d_in[6];
  float* out = (float*)d_out;
  char* ws = (char*)d_ws;

  float* maskBias = (float*)ws;                       // 8192 f32
  float* maskMul = (float*)(ws + (32 << 10));         // 8192 f32
  u16* w_in_b = (u16*)(ws + (64 << 10));              // 3072*1024
  u16* w_out_b = w_in_b + 3145728;                    // 1024*1024
  u16* xb = w_out_b + 1048576;                        // 8192*1024 (reused as attn_out)
  u16* qbuf = xb + 8388608;                           // [b][h][n][64]
  u16* kbuf = qbuf + 8388608;
  u16* vT = kbuf + 8388608;                           // [b][h][64][n'] (key-permuted)

  fused_prep_kernel<<<2048, 256, 0, stream>>>(x, w_in, w_out, mask,
                                              xb, w_in_b, w_out_b, maskBias, maskMul);
  gemm_qkv_kernel<<<dim3(24, 64), 256, 0, stream>>>(xb, w_in_b, b_in, qbuf, kbuf, vT);
  rope_kernel<<<1024, 256, 0, stream>>>(qbuf, kbuf, freqs);
  attn_kernel<<<dim3(64, 8), 256, 0, stream>>>(qbuf, kbuf, vT, maskBias, xb);
  gemm_out_kernel<<<dim3(8, 64), 256, 0, stream>>>(xb, w_out_b, b_out, maskMul, out);
}